// Round 8
// baseline (188.824 us; speedup 1.0000x reference)
//
#include <hip/hip_runtime.h>

// DeformConv fused R8: R6 base + fragment-order LDS B (lane-linear reads),
// XOR-swizzled A/band tiles, phase-1 band loads, software-pipelined prefetch.
// B=4, C=128, H=W=96, O=128, 3x3 s1 p1 d1, G=1.
#define CIN   128
#define HH    96
#define WW    96
#define OUTC  128
#define HWSZ  9216
#define KK    9
#define KTOT  1152

typedef __bf16 bf16x8 __attribute__((ext_vector_type(8)));
typedef float  f32x4  __attribute__((ext_vector_type(4)));

__device__ __forceinline__ unsigned short f2bf(float f) {
  unsigned u = __builtin_bit_cast(unsigned, f);
  u += 0x7fffu + ((u >> 16) & 1u);               // RNE
  return (unsigned short)(u >> 16);
}
__device__ __forceinline__ float bf2f_lo(unsigned w) {
  unsigned u = w << 16;
  return __builtin_bit_cast(float, u);
}
__device__ __forceinline__ float bf2f_hi(unsigned w) {
  unsigned u = w & 0xffff0000u;
  return __builtin_bit_cast(float, u);
}
__device__ __forceinline__ unsigned pack_bf(float v0, float v1) {
  unsigned u0 = __builtin_bit_cast(unsigned, v0) + 0x8000u;
  unsigned u1 = __builtin_bit_cast(unsigned, v1) + 0x8000u;
  return __builtin_amdgcn_perm(u1, u0, 0x07060302u);
}

// ws layout (u16 offsets):
//   wtt   bf16 tiled [tap][ks][nt(8)][lane(64)][8]  @ 0       (147456)
//         lane = quad*16 + l15 ; o = nt*16+l15 ; c = ks*32+quad*8+j
//   wt2t  bf16 tiled [tap][ks][nt2(2)][lane(64)][8] @ 147456  (36864)
//   bias32 f32[32]                                  @ 184320  (64 u16)
//   xn    bf16[4][9216][128]  @ 184384   (NHWC)
//   x2n   bf16[4][9216][128]  @ 184384+4718592
#define WT2T_O 147456
#define BIAS_O 184320
#define XN_O   184384
#define X2N_O  (184384 + 4718592)

__global__ __launch_bounds__(256) void prep_all(
    const float* __restrict__ x, const float* __restrict__ x2,
    const float* __restrict__ offw, const float* __restrict__ maskw,
    const float* __restrict__ defw, const float* __restrict__ offb,
    const float* __restrict__ maskb, void* __restrict__ wsv) {
  int bid = blockIdx.x;
  int t = threadIdx.x;
  if (bid < 1152) {
    __shared__ unsigned short tile[64][138];
    int tsel = bid / 576;
    int rem = bid - tsel * 576;
    int b = rem / 144;
    int hw0 = (rem % 144) * 64;
    const float* src = tsel ? x2 : x;
    unsigned short* dst = (unsigned short*)wsv + (tsel ? X2N_O : XN_O);
    int px = t & 63, cg = t >> 6;
#pragma unroll
    for (int q = 0; q < 16; ++q) {
      int c = cg * 32 + 2 * q;
      float f0 = src[((size_t)(b * CIN + c))     * HWSZ + hw0 + px];
      float f1 = src[((size_t)(b * CIN + c + 1)) * HWSZ + hw0 + px];
      *(unsigned*)&tile[px][c] = pack_bf(f0, f1);
    }
    __syncthreads();
    unsigned* drow = (unsigned*)(dst + ((size_t)(b * HWSZ + hw0)) * 128);
#pragma unroll
    for (int k = 0; k < 16; ++k) {
      int e = t + 256 * k;
      int pxx = e >> 6, j = e & 63;
      unsigned v = *(const unsigned*)&tile[pxx][2 * j];
      drow[(size_t)pxx * 64 + j] = v;
    }
    return;
  }
  unsigned short* wtt  = (unsigned short*)wsv;
  unsigned short* wt2t = wtt + WT2T_O;
  float* bias32 = (float*)(wtt + BIAS_O);
  int idx = (bid - 1152) * 256 + t;
  if (idx < OUTC * KTOT) {
    int o = idx / KTOT, r = idx - o * KTOT;
    int c = r / KK, tap = r - c * KK;
    int nt = o >> 4, l15o = o & 15;
    int ks = c >> 5, quad = (c >> 3) & 3, j = c & 7;
    wtt[(size_t)(((tap * 4 + ks) * 8 + nt) * 64 + quad * 16 + l15o) * 8 + j] =
        f2bf(defw[idx]);
  } else if (idx < OUTC * KTOT + 32 * KTOT) {
    int jj = idx - OUTC * KTOT;
    int oc = jj / KTOT, r = jj - oc * KTOT;
    int c = r / KK, tap = r - c * KK;
    float v = 0.f;
    if (oc < 18)      v = offw[jj];
    else if (oc < 27) v = maskw[jj - 18 * KTOT];
    int nt2 = oc >> 4, l15o = oc & 15;
    int ks = c >> 5, quad = (c >> 3) & 3, j = c & 7;
    wt2t[(size_t)(((tap * 4 + ks) * 2 + nt2) * 64 + quad * 16 + l15o) * 8 + j] =
        f2bf(v);
  } else if (idx < OUTC * KTOT + 32 * KTOT + 32) {
    int j = idx - OUTC * KTOT - 32 * KTOT;
    float v = 0.f;
    if (j < 18) v = offb[j]; else if (j < 27) v = maskb[j - 18];
    bias32[j] = v;
  }
}

#define BAND_ROWS 66
#define BAND_SLOTS (BAND_ROWS * 16)   // uint4 slots

__global__ __launch_bounds__(256, 2) void fused(
    const float* __restrict__ defb, const void* __restrict__ wsv,
    float* __restrict__ out) {
  const unsigned short* wtt  = (const unsigned short*)wsv;
  const unsigned short* wt2t = wtt + WT2T_O;
  const float* bias32 = (const float*)(wtt + BIAS_O);
  const unsigned short* xn  = wtt + XN_O;
  const unsigned short* x2n = wtt + X2N_O;

  __shared__ __align__(16) unsigned short sB[16384];  // 32 KB: frag-order B tap-tile
  __shared__ __align__(16) unsigned valw[BAND_ROWS * 64]; // 16.9 KB: A/band, swizzled
  __shared__ __align__(16) unsigned omsx[2304];       // 9.2 KB: om / prm / epilogue

  int t = threadIdx.x;
  int w = t >> 6;
  int l = t & 63;
  int l15 = l & 15, quad = l >> 4;
  int rb = blockIdx.x;
  int bid = (rb & 7) * 72 + (rb >> 3);     // XCD swizzle
  int b = bid / 144;
  int pblk = (bid % 144) * 64;

  int px_m = w * 16 + l15;                 // this lane's m-row pixel
  int gp = pblk + px_m;
  int pw_m = gp % WW;

  // ===== phase 1: offset/mask GEMM via x2 band loads =====
  const unsigned short* x2nb = x2n + ((size_t)b * HWSZ) * 128;
  float* omv = (float*)omsx;

  uint4 brg[5];
  auto band_load = [&](int ky, uint4* r) {
#pragma unroll
    for (int i = 0; i < 5; ++i) {
      int cc = t + 256 * i;
      if (cc < BAND_SLOTS) {
        int row = cc >> 4, c16 = cc & 15;
        int rr = pblk + (ky - 1) * WW - 1 + row;
        bool ok = ((unsigned)rr < HWSZ);
        uint4 v = make_uint4(0u, 0u, 0u, 0u);
        if (ok) v = *(const uint4*)(x2nb + ((size_t)rr << 7) + c16 * 8);
        r[i] = v;
      }
    }
  };
  auto band_store = [&](uint4* r) {
#pragma unroll
    for (int i = 0; i < 5; ++i) {
      int cc = t + 256 * i;
      if (cc < BAND_SLOTS) {
        int row = cc >> 4, c16 = cc & 15;
        *(uint4*)&valw[row * 64 + ((c16 * 4) ^ ((row & 7) << 2))] = r[i];
      }
    }
  };

  band_load(0, brg);
  band_store(brg);
  __syncthreads();

  f32x4 oa0 = {0.f, 0.f, 0.f, 0.f};
  f32x4 oa1 = {0.f, 0.f, 0.f, 0.f};
  for (int ky = 0; ky < 3; ++ky) {
    uint4 nrg[5];
    if (ky < 2) band_load(ky + 1, nrg);        // in flight during MFMAs
#pragma unroll
    for (int kx = 0; kx < 3; ++kx) {
      int tap = ky * 3 + kx;
      bool okx = ((unsigned)(pw_m + kx - 1) < WW);
      int bi = px_m + kx;                      // band row
#pragma unroll
      for (int ks = 0; ks < 4; ++ks) {
        int col4 = ks * 16 + quad * 4;
        bf16x8 af = *(const bf16x8*)&valw[bi * 64 + (col4 ^ ((bi & 7) << 2))];
        if (!okx) af = (bf16x8){};
        const unsigned short* bp = wt2t + (size_t)(((tap * 4 + ks) * 2) * 64 + l) * 8;
        bf16x8 b0 = *(const bf16x8*)bp;
        bf16x8 b1 = *(const bf16x8*)(bp + 512);
        oa0 = __builtin_amdgcn_mfma_f32_16x16x32_bf16(af, b0, oa0, 0, 0, 0);
        oa1 = __builtin_amdgcn_mfma_f32_16x16x32_bf16(af, b1, oa1, 0, 0, 0);
      }
    }
    __syncthreads();                           // band reads done
    if (ky < 2) {
      band_store(nrg);
      __syncthreads();                         // new band visible
    }
  }
  // dump om (+bias): om[oc][px], oc = nt*16+l15, px = w*16+quad*4+r
#pragma unroll
  for (int nt = 0; nt < 2; ++nt) {
    f32x4 a = nt ? oa1 : oa0;
    int oc = nt * 16 + l15;
    float bia = bias32[oc];
#pragma unroll
    for (int r = 0; r < 4; ++r)
      omv[oc * 64 + w * 16 + quad * 4 + r] = a[r] + bia;
  }
  __syncthreads();

  // ===== phase 2: bilinear params (two-step; prm overwrites om) =====
  uint4 pkreg[3];
#pragma unroll
  for (int i = 0; i < 3; ++i) {
    int e = t + 256 * i;
    if (e < KK * 64) {
      int tap = e >> 6, pp = e & 63;
      int gp2 = pblk + pp;
      int h = gp2 / WW, ww_ = gp2 % WW;
      float dy = omv[(2 * tap) * 64 + pp], dx = omv[(2 * tap + 1) * 64 + pp];
      float mr = omv[(18 + tap) * 64 + pp];
      float m = 1.f / (1.f + __expf(-mr));
      float py  = (float)(h + tap / 3 - 1) + dy;
      float pxx = (float)(ww_ + tap % 3 - 1) + dx;
      float y0f = floorf(py), x0f = floorf(pxx);
      int y0 = (int)y0f, x0 = (int)x0f;
      float ly = py - y0f, lx = pxx - x0f;
      int y1 = y0 + 1, x1 = x0 + 1;
      bool vy0 = (unsigned)y0 < HH, vy1 = (unsigned)y1 < HH;
      bool vx0 = (unsigned)x0 < WW, vx1 = (unsigned)x1 < WW;
      int cy0 = min(max(y0, 0), HH - 1), cy1 = min(max(y1, 0), HH - 1);
      int cx0 = min(max(x0, 0), WW - 1), cx1 = min(max(x1, 0), WW - 1);
      unsigned i00 = cy0 * WW + cx0, i01 = cy0 * WW + cx1;
      unsigned i10 = cy1 * WW + cx0, i11 = cy1 * WW + cx1;
      float w00 = (vy0 && vx0) ? m * (1.f - ly) * (1.f - lx) : 0.f;
      float w01 = (vy0 && vx1) ? m * (1.f - ly) * lx         : 0.f;
      float w10 = (vy1 && vx0) ? m * ly * (1.f - lx)         : 0.f;
      float w11 = (vy1 && vx1) ? m * ly * lx                 : 0.f;
      pkreg[i].x = i00 | ((unsigned)f2bf(w00) << 16);
      pkreg[i].y = i01 | ((unsigned)f2bf(w01) << 16);
      pkreg[i].z = i10 | ((unsigned)f2bf(w10) << 16);
      pkreg[i].w = i11 | ((unsigned)f2bf(w11) << 16);
    }
  }
  __syncthreads();
  uint4* prm = (uint4*)omsx;                  // prm[tap*64+px]
#pragma unroll
  for (int i = 0; i < 3; ++i) {
    int e = t + 256 * i;
    if (e < KK * 64) prm[e] = pkreg[i];
  }
  __syncthreads();

  // ===== phase 3: deformable GEMM, pipelined =====
  f32x4 acc[8];
#pragma unroll
  for (int nt = 0; nt < 8; ++nt) acc[nt] = (f32x4){0.f, 0.f, 0.f, 0.f};
  const unsigned short* xnb = xn + ((size_t)b * HWSZ) * 128;

  uint4 pk[4], v[4][4], bB[8];
  auto issue_tap = [&](int tap) {
#pragma unroll
    for (int G = 0; G < 4; ++G)
      pk[G] = prm[tap * 64 + w * 16 + G * 4 + quad];   // b128 broadcast
#pragma unroll
    for (int G = 0; G < 4; ++G) {
      const unsigned* pc = (const unsigned*)&pk[G];
#pragma unroll
      for (int cr = 0; cr < 4; ++cr)
        v[G][cr] = *(const uint4*)(xnb + ((size_t)(pc[cr] & 0xffffu) << 7) + l15 * 8);
    }
    const unsigned short* wsrc = wtt + (size_t)tap * 16384;
#pragma unroll
    for (int j = 0; j < 8; ++j)
      bB[j] = *(const uint4*)(wsrc + (size_t)(j * 256 + t) * 8);
  };

  issue_tap(0);
  for (int tap = 0; tap < KK; ++tap) {
    // combine corners -> A tile (swizzled)
#pragma unroll
    for (int G = 0; G < 4; ++G) {
      const unsigned* pc = (const unsigned*)&pk[G];
      float f[8];
#pragma unroll
      for (int j = 0; j < 8; ++j) f[j] = 0.f;
#pragma unroll
      for (int cr = 0; cr < 4; ++cr) {
        float wc = bf2f_hi(pc[cr]);
        const unsigned* a = (const unsigned*)&v[G][cr];
#pragma unroll
        for (int j = 0; j < 4; ++j) {
          f[2 * j]     += wc * bf2f_lo(a[j]);
          f[2 * j + 1] += wc * bf2f_hi(a[j]);
        }
      }
      unsigned od[4];
#pragma unroll
      for (int j = 0; j < 4; ++j) od[j] = pack_bf(f[2 * j], f[2 * j + 1]);
      int row = w * 16 + G * 4 + quad;
      *(uint4*)&valw[row * 64 + ((l15 * 4) ^ ((row & 7) << 2))] =
          make_uint4(od[0], od[1], od[2], od[3]);
    }
    // store B tile (lane-linear fragment order)
#pragma unroll
    for (int j = 0; j < 8; ++j)
      ((uint4*)sB)[j * 256 + t] = bB[j];
    __syncthreads();
    if (tap < 8) issue_tap(tap + 1);           // loads fly under MFMAs
    bf16x8 af[4];
#pragma unroll
    for (int ks = 0; ks < 4; ++ks) {
      int row = w * 16 + l15;
      af[ks] = *(const bf16x8*)&valw[row * 64 +
                 ((ks * 16 + quad * 4) ^ ((l15 & 7) << 2))];
    }
#pragma unroll
    for (int ks = 0; ks < 4; ++ks)
#pragma unroll
      for (int nt = 0; nt < 8; ++nt) {
        bf16x8 bb = *(const bf16x8*)&sB[(size_t)(((ks * 8 + nt) * 64) + l) * 8];
        acc[nt] = __builtin_amdgcn_mfma_f32_16x16x32_bf16(af[ks], bb, acc[nt], 0, 0, 0);
      }
    __syncthreads();
  }

  // ===== phase 4: epilogue (reuses omsx as f32[32][72]) =====
  float* fb = (float*)omsx;
  for (int r = 0; r < 4; ++r) {
    f32x4 a0 = acc[2 * r], a1 = acc[2 * r + 1];
    float db0 = defb[r * 32 + l15];
    float db1 = defb[r * 32 + 16 + l15];
    if (r) __syncthreads();
#pragma unroll
    for (int reg = 0; reg < 4; ++reg) {
      fb[l15 * 72        + w * 16 + quad * 4 + reg] = a0[reg] + db0;
      fb[(16 + l15) * 72 + w * 16 + quad * 4 + reg] = a1[reg] + db1;
    }
    __syncthreads();
    int row = t >> 4;
    int col4 = (t & 15) * 4;
#pragma unroll
    for (int hrow = 0; hrow < 2; ++hrow) {
      int rr = row + hrow * 16;
      float4 vv = *(float4*)&fb[rr * 72 + col4];
      *(float4*)&out[((size_t)b * OUTC + r * 32 + rr) * HWSZ + pblk + col4] = vv;
    }
  }
}

extern "C" void kernel_launch(void* const* d_in, const int* in_sizes, int n_in,
                              void* d_out, int out_size, void* d_ws, size_t ws_size,
                              hipStream_t stream) {
  const float* x     = (const float*)d_in[0];
  const float* x2    = (const float*)d_in[1];
  const float* offw  = (const float*)d_in[2];
  const float* offb  = (const float*)d_in[3];
  const float* maskw = (const float*)d_in[4];
  const float* maskb = (const float*)d_in[5];
  const float* defw  = (const float*)d_in[6];
  const float* defb  = (const float*)d_in[7];
  float* out = (float*)d_out;

  hipLaunchKernelGGL(prep_all, dim3(1873), dim3(256), 0, stream,
                     x, x2, offw, maskw, defw, offb, maskb, d_ws);
  hipLaunchKernelGGL(fused, dim3(576), dim3(256), 0, stream, defb, d_ws, out);
}